// Round 6
// baseline (196.312 us; speedup 1.0000x reference)
//
#include <hip/hip_runtime.h>
#include <hip/hip_bf16.h>
#include <stdint.h>

#define DM   1024
#define FF   4096
#define NH   16
#define DK   64
#define SEQ  512
#define NTOK 4096

typedef __attribute__((ext_vector_type(8))) unsigned short ushort8;
typedef __attribute__((ext_vector_type(4))) unsigned short ushort4v;
typedef __attribute__((ext_vector_type(8))) short bf16x8;
typedef __attribute__((ext_vector_type(4))) float f32x4;

__device__ __forceinline__ float bf2f(unsigned short u) {
  union { unsigned int i; float f; } v; v.i = ((unsigned int)u) << 16; return v.f;
}
__device__ __forceinline__ unsigned short f2bf(float f) {
  union { float fl; unsigned int i; } v; v.fl = f;
  v.i += 0x7fffu + ((v.i >> 16) & 1u);   // RNE
  return (unsigned short)(v.i >> 16);
}

__device__ __forceinline__ void gload16(const unsigned short* g, unsigned short* l) {
  __builtin_amdgcn_global_load_lds(
      (const __attribute__((address_space(1))) unsigned int*)g,
      (__attribute__((address_space(3))) unsigned int*)l, 16, 0, 0);
}

// ---------------- f32 -> bf16 elementwise convert ------------------------------
__global__ __launch_bounds__(256)
void f32_to_bf16(const float* __restrict__ in, unsigned short* __restrict__ out,
                 long n) {
  long i = ((long)blockIdx.x * 256 + threadIdx.x) * 4;
  if (i + 3 < n) {
    f32x4 v = *(const f32x4*)(in + i);
    ushort4v o;
#pragma unroll
    for (int j = 0; j < 4; j++) o[j] = f2bf(v[j]);
    *(ushort4v*)(out + i) = o;
  }
}

// ---------------- transpose + convert: out[n][k](bf16) = in[k][n](f32) ---------
__global__ void transpose_f2b(const float* __restrict__ in, int ldin,
                              unsigned short* __restrict__ out, int ldout) {
  __shared__ unsigned short tile[32][33];
  const int tx = threadIdx.x, ty = threadIdx.y;
  const long r0 = (long)blockIdx.y * 32, c0 = (long)blockIdx.x * 32;
#pragma unroll
  for (int i = 0; i < 4; i++)
    tile[ty + i * 8][tx] = f2bf(in[(r0 + ty + i * 8) * ldin + c0 + tx]);
  __syncthreads();
#pragma unroll
  for (int i = 0; i < 4; i++)
    out[(c0 + ty + i * 8) * ldout + r0 + tx] = tile[tx][ty + i * 8];
}

// ---------------- V transpose per (b,h): Vt[bh][d][s] = V[b, s, h, d] (bf16) ---
__global__ void transpose_v(const unsigned short* __restrict__ QKV,
                            unsigned short* __restrict__ Vt) {
  __shared__ unsigned short tile[32][33];
  const int tx = threadIdx.x, ty = threadIdx.y;
  const int bh = blockIdx.z, b = bh >> 4, h = bh & 15;
  const int s0 = blockIdx.y * 32, d0 = blockIdx.x * 32;
  const unsigned short* inb = QKV + (long)(b * SEQ) * 3072 + 2048 + h * 64;
#pragma unroll
  for (int i = 0; i < 4; i++)
    tile[ty + i * 8][tx] = inb[(long)(s0 + ty + i * 8) * 3072 + d0 + tx];
  __syncthreads();
#pragma unroll
  for (int i = 0; i < 4; i++)
    Vt[(long)bh * (DK * SEQ) + (long)(d0 + ty + i * 8) * SEQ + s0 + tx] =
        tile[tx][ty + i * 8];
}

// ---------------- concat 3 f32 bias vectors ------------------------------------
__global__ void concat3(const float* __restrict__ a, const float* __restrict__ b,
                        const float* __restrict__ c, float* __restrict__ o) {
  int i = blockIdx.x * 256 + threadIdx.x;
  if (i < 3072)
    o[i] = (i < 1024) ? a[i] : ((i < 2048) ? b[i - 1024] : c[i - 2048]);
}

// ============== 256x256 BK=64 8-phase-style bf16 GEMM (m201 schedule) ==========
// 8 waves (2Mx4N), per-wave 128x64 out.  LDS 128KB: A/B each [2buf][2ks][256][32]
// with the proven zero-conflict slot swizzle (src pre-swizzle + ds_read swizzle).
// Per K-tile: 4 phases, each = {1 quarter-stage (2 gloads), ds_reads, s_barrier,
// 16 MFMA in setprio, s_barrier}.  Quarter-staging rotation (into just-consumed
// quarters): ph0: A-ks1(t+1), ph1: B-ks1(t+1), ph2: A-ks0(t+2), ph3: B-ks0(t+2).
// ONE counted vmcnt(4) per K-tile at ph3's pre-MFMA barrier (steady outstanding
// = 12, leaves newest 4) -> every load has >= 4 phases of latency slack.
template <bool RELU, bool PARTIAL>
__global__ __launch_bounds__(512, 2)
void gemm256(const unsigned short* __restrict__ A, int lda,
             const unsigned short* __restrict__ B, int ldb,
             const float* __restrict__ bias,
             unsigned short* __restrict__ C,
             unsigned short* __restrict__ P1,
             unsigned short* __restrict__ P2,
             unsigned short* __restrict__ P3,
             int ldc, int nTN) {
  __shared__ unsigned short sm[65536];   // A: [0,32768), B: [32768,65536) elements
  const int tid = threadIdx.x;
  const int lane = tid & 63;
  const int wid = tid >> 6;
  const int wr = wid >> 2, wc = wid & 3;

  const unsigned int T = gridDim.x;
  const unsigned int q8 = T >> 3;
  const unsigned int x = blockIdx.x;
  const unsigned int swz = (x & 7) * q8 + (x >> 3);
  const long bm = (long)(swz / nTN) * 256;
  const long bn = (long)(swz % nTN) * 256;
  const long kbase = (long)blockIdx.y * 1024;

  f32x4 acc[8][4];
#pragma unroll
  for (int mf = 0; mf < 8; mf++)
#pragma unroll
    for (int nf = 0; nf < 4; nf++) acc[mf][nf] = f32x4{0.f, 0.f, 0.f, 0.f};

  // staging: 512 thr cover 128 rows x 32 cols (8KB) per gload call
  const int strow = tid >> 2;                                  // 0..127
  const int scol = (((tid & 3) ^ ((tid >> 3) & 3)) << 3);      // pre-swizzled src
  const unsigned short* pA = A + (bm + strow) * lda + kbase + scol;
  const unsigned short* pB = B + (bn + strow) * ldb + kbase + scol;
  unsigned short* dA = sm + tid * 8;
  unsigned short* dB = sm + 32768 + tid * 8;

  const int g = lane >> 4;
  int offA[8], offB[4];
#pragma unroll
  for (int mf = 0; mf < 8; mf++) {
    const int rm = wr * 128 + mf * 16 + (lane & 15);
    offA[mf] = rm * 32 + ((g ^ ((rm >> 1) & 3)) << 3);
  }
#pragma unroll
  for (int nf = 0; nf < 4; nf++) {
    const int rb = wc * 64 + nf * 16 + (lane & 15);
    offB[nf] = rb * 32 + ((g ^ ((rb >> 1) & 3)) << 3);
  }

#define GAQ(kt, ks) do {                                                       \
    gload16(pA + (long)(kt) * 64 + (ks) * 32,                                  \
            dA + ((kt) & 1) * 16384 + (ks) * 8192);                            \
    gload16(pA + (long)128 * lda + (long)(kt) * 64 + (ks) * 32,                \
            dA + ((kt) & 1) * 16384 + (ks) * 8192 + 4096);                     \
  } while (0)
#define GBQ(kt, ks) do {                                                       \
    gload16(pB + (long)(kt) * 64 + (ks) * 32,                                  \
            dB + ((kt) & 1) * 16384 + (ks) * 8192);                            \
    gload16(pB + (long)128 * ldb + (long)(kt) * 64 + (ks) * 32,                \
            dB + ((kt) & 1) * 16384 + (ks) * 8192 + 4096);                     \
  } while (0)
#define BAR asm volatile("s_barrier" ::: "memory")
#define BARV4 asm volatile("s_waitcnt vmcnt(4)\ns_barrier" ::: "memory")
#define MF16(AR, BR, MO)                                                      \
  do {                                                                        \
    __builtin_amdgcn_s_setprio(1);                                            \
    _Pragma("unroll")                                                         \
    for (int mf = 0; mf < 4; mf++)                                            \
      _Pragma("unroll")                                                       \
      for (int nf = 0; nf < 4; nf++)                                          \
        acc[(MO) + mf][nf] = __builtin_amdgcn_mfma_f32_16x16x32_bf16(         \
            AR[mf], BR[nf], acc[(MO) + mf][nf], 0, 0, 0);                     \
    __builtin_amdgcn_s_setprio(0);                                            \
  } while (0)

  // prologue: tile0 full (8), tile1 ks0 quarters (4); wait tile0 (leave 4)
  GAQ(0, 0); GAQ(0, 1); GBQ(0, 0); GBQ(0, 1);
  GAQ(1, 0); GBQ(1, 0);
  BARV4;

  for (int t = 0; t < 16; ++t) {
    const unsigned short* smA = sm + (t & 1) * 16384;
    const unsigned short* smB = sm + 32768 + (t & 1) * 16384;
    const int k1 = (t + 1) & 15;   // tail wraps: restage, never read (safe)
    const int k2 = (t + 2) & 15;
    bf16x8 a_[4], b0[4], b1[4];

    // ---- phase 0: MFMA(ks0, mf0-3) ----
    GAQ(k1, 1);
#pragma unroll
    for (int mf = 0; mf < 4; mf++) a_[mf] = *(const bf16x8*)(smA + offA[mf]);
#pragma unroll
    for (int nf = 0; nf < 4; nf++) b0[nf] = *(const bf16x8*)(smB + offB[nf]);
    BAR;
    MF16(a_, b0, 0);
    BAR;

    // ---- phase 1: MFMA(ks0, mf4-7) ----
    GBQ(k1, 1);
#pragma unroll
    for (int mf = 0; mf < 4; mf++) a_[mf] = *(const bf16x8*)(smA + offA[4 + mf]);
    BAR;
    MF16(a_, b0, 4);
    BAR;

    // ---- phase 2: MFMA(ks1, mf0-3) ----
    GAQ(k2, 0);
#pragma unroll
    for (int mf = 0; mf < 4; mf++) a_[mf] = *(const bf16x8*)(smA + 8192 + offA[mf]);
#pragma unroll
    for (int nf = 0; nf < 4; nf++) b1[nf] = *(const bf16x8*)(smB + 8192 + offB[nf]);
    BAR;
    MF16(a_, b1, 0);
    BAR;

    // ---- phase 3: MFMA(ks1, mf4-7); counted vmcnt guarantees tile t+1 ----
    GBQ(k2, 0);
#pragma unroll
    for (int mf = 0; mf < 4; mf++) a_[mf] = *(const bf16x8*)(smA + 8192 + offA[4 + mf]);
    BARV4;
    MF16(a_, b1, 4);
    BAR;
  }
#undef GAQ
#undef GBQ
#undef BAR
#undef BARV4
#undef MF16

  unsigned short* Cw = C;
  if (PARTIAL) {
    const int kc = blockIdx.y;
    Cw = (kc == 0) ? C : (kc == 1) ? P1 : (kc == 2) ? P2 : P3;
  }
  const long r0 = bm + wr * 128 + ((lane >> 4) << 2);
  const int c0 = (int)bn + wc * 64 + (lane & 15);
#pragma unroll
  for (int nf = 0; nf < 4; nf++) {
    const int col = c0 + nf * 16;
    const float bv = PARTIAL ? 0.f : bias[col];
#pragma unroll
    for (int mf = 0; mf < 8; mf++) {
#pragma unroll
      for (int i = 0; i < 4; i++) {
        float v = acc[mf][nf][i] + bv;
        if (RELU) v = fmaxf(v, 0.f);
        Cw[(r0 + mf * 16 + i) * ldc + col] = f2bf(v);
      }
    }
  }
}

// =================== flash attention: 8 waves, static softmax ===================
__global__ __launch_bounds__(512)
void attn_kernel(const unsigned short* __restrict__ QKV,
                 const unsigned short* __restrict__ Vt,
                 unsigned short* __restrict__ CTX) {
  const int qt = blockIdx.x;          // 0..3
  const int bh = blockIdx.y;          // 0..127
  const int b = bh >> 4, h = bh & 15;
  const int tid = threadIdx.x;
  const int lane = tid & 63;
  const int wid = tid >> 6;           // 0..7

  __shared__ unsigned short Ks[64][72];
  __shared__ unsigned short Vs[64][72];
  __shared__ unsigned short Ps[8][16][72];

  const int qrow0 = qt * 128 + wid * 16;
  const unsigned short* Qb = QKV + (long)(b * SEQ + qrow0) * 3072 + h * 64;
  bf16x8 aq[2];
#pragma unroll
  for (int ks = 0; ks < 2; ks++)
    aq[ks] = *(const bf16x8*)(Qb + (long)(lane & 15) * 3072 + ks * 32 +
                              (lane >> 4) * 8);

  f32x4 acc_o[4];
#pragma unroll
  for (int n = 0; n < 4; n++) acc_o[n] = f32x4{0.f, 0.f, 0.f, 0.f};
  float rsum[4] = {0.f, 0.f, 0.f, 0.f};

  const int sr = tid >> 3;            // 0..63
  const int sc = (tid & 7) * 8;       // 0..56
  const unsigned short* Kg = QKV + (long)(b * SEQ) * 3072 + 1024 + h * 64 + sc;
  const unsigned short* Vg = Vt + (long)bh * (DK * SEQ) + (long)sr * SEQ + sc;

  ushort8 kr = *(const ushort8*)(Kg + (long)sr * 3072);
  ushort8 vr = *(const ushort8*)(Vg);

#pragma unroll
  for (int c = 0; c < 8; ++c) {
    __syncthreads();
    *(ushort8*)(&Ks[sr][sc]) = kr;
    *(ushort8*)(&Vs[sr][sc]) = vr;
    if (c < 7) {
      kr = *(const ushort8*)(Kg + (long)((c + 1) * 64 + sr) * 3072);
      vr = *(const ushort8*)(Vg + (c + 1) * 64);
    }
    __syncthreads();

    f32x4 s[4];
#pragma unroll
    for (int n = 0; n < 4; n++) s[n] = f32x4{0.f, 0.f, 0.f, 0.f};
#pragma unroll
    for (int ks = 0; ks < 2; ks++) {
      bf16x8 kf[4];
#pragma unroll
      for (int n = 0; n < 4; n++)
        kf[n] = *(const bf16x8*)(&Ks[n * 16 + (lane & 15)][ks * 32 + (lane >> 4) * 8]);
#pragma unroll
      for (int n = 0; n < 4; n++)
        s[n] = __builtin_amdgcn_mfma_f32_16x16x32_bf16(aq[ks], kf[n], s[n], 0, 0, 0);
    }

#pragma unroll
    for (int n = 0; n < 4; n++) {
#pragma unroll
      for (int i = 0; i < 4; i++) {
        const float p = __expf(s[n][i] * 0.125f);
        rsum[i] += p;
        Ps[wid][(lane >> 4) * 4 + i][n * 16 + (lane & 15)] = f2bf(p);
      }
    }

#pragma unroll
    for (int ks = 0; ks < 2; ks++) {
      bf16x8 pa = *(const bf16x8*)(&Ps[wid][lane & 15][ks * 32 + (lane >> 4) * 8]);
      bf16x8 vf[4];
#pragma unroll
      for (int n = 0; n < 4; n++)
        vf[n] = *(const bf16x8*)(&Vs[n * 16 + (lane & 15)][ks * 32 + (lane >> 4) * 8]);
#pragma unroll
      for (int n = 0; n < 4; n++)
        acc_o[n] = __builtin_amdgcn_mfma_f32_16x16x32_bf16(pa, vf[n], acc_o[n], 0, 0, 0);
    }
  }

#pragma unroll
  for (int i = 0; i < 4; i++) {
#pragma unroll
    for (int off = 1; off < 16; off <<= 1) rsum[i] += __shfl_xor(rsum[i], off, 64);
  }

  const long orow0 = (long)(b * SEQ + qrow0);
#pragma unroll
  for (int i = 0; i < 4; i++) {
    const float inv = 1.f / rsum[i];
    const long r = orow0 + (lane >> 4) * 4 + i;
#pragma unroll
    for (int n = 0; n < 4; n++)
      CTX[r * DM + h * 64 + n * 16 + (lane & 15)] = f2bf(acc_o[n][i] * inv);
  }
}

// ---------------- LN1: LN(X(bf16) + R(f32)); writes f32 + bf16 -----------------
__global__ __launch_bounds__(256)
void ln1_kernel(const unsigned short* __restrict__ X,
                const float* __restrict__ R,
                const float* __restrict__ g,
                const float* __restrict__ be,
                float* __restrict__ Of,
                unsigned short* __restrict__ Ob) {
  const int t = blockIdx.x;
  const int tid = threadIdx.x;
  const long base = (long)t * DM + tid * 4;
  __shared__ float red[8];

  ushort4v xv = *(const ushort4v*)(X + base);
  f32x4 rv = *(const f32x4*)(R + base);
  float v[4];
#pragma unroll
  for (int j = 0; j < 4; j++) v[j] = bf2f(xv[j]) + rv[j];
  float s = v[0] + v[1] + v[2] + v[3];
  float q = v[0] * v[0] + v[1] * v[1] + v[2] * v[2] + v[3] * v[3];
#pragma unroll
  for (int off = 1; off < 64; off <<= 1) {
    s += __shfl_xor(s, off, 64);
    q += __shfl_xor(q, off, 64);
  }
  if ((tid & 63) == 0) { red[tid >> 6] = s; red[4 + (tid >> 6)] = q; }
  __syncthreads();
  s = red[0] + red[1] + red[2] + red[3];
  q = red[4] + red[5] + red[6] + red[7];
  const float mu = s * (1.f / DM);
  const float var = q * (1.f / DM) - mu * mu;
  const float rstd = rsqrtf(fmaxf(var, 0.f) + 1e-5f);

  f32x4 gv = *(const f32x4*)(g + tid * 4);
  f32x4 bv = *(const f32x4*)(be + tid * 4);
  f32x4 of;
  ushort4v ob;
#pragma unroll
  for (int j = 0; j < 4; j++) {
    of[j] = (v[j] - mu) * rstd * gv[j] + bv[j];
    ob[j] = f2bf(of[j]);
  }
  *(f32x4*)(Of + base) = of;
  *(ushort4v*)(Ob + base) = ob;
}

// ---------------- LN2: LN(sum(4 bf16 partials) + b2 + X1f); writes f32 ---------
__global__ __launch_bounds__(256)
void ln2_kernel(const unsigned short* __restrict__ P0,
                const unsigned short* __restrict__ P1,
                const unsigned short* __restrict__ P2,
                const unsigned short* __restrict__ P3,
                const float* __restrict__ b2,
                const float* __restrict__ R,
                const float* __restrict__ g,
                const float* __restrict__ be,
                float* __restrict__ O) {
  const int t = blockIdx.x;
  const int tid = threadIdx.x;
  const long base = (long)t * DM + tid * 4;
  __shared__ float red[8];

  ushort4v p0 = *(const ushort4v*)(P0 + base);
  ushort4v p1 = *(const ushort4v*)(P1 + base);
  ushort4v p2 = *(const ushort4v*)(P2 + base);
  ushort4v p3 = *(const ushort4v*)(P3 + base);
  f32x4 bb = *(const f32x4*)(b2 + tid * 4);
  f32x4 rv = *(const f32x4*)(R + base);
  float v[4];
#pragma unroll
  for (int j = 0; j < 4; j++)
    v[j] = bf2f(p0[j]) + bf2f(p1[j]) + bf2f(p2[j]) + bf2f(p3[j]) + bb[j] + rv[j];
  float s = v[0] + v[1] + v[2] + v[3];
  float q = v[0] * v[0] + v[1] * v[1] + v[2] * v[2] + v[3] * v[3];
#pragma unroll
  for (int off = 1; off < 64; off <<= 1) {
    s += __shfl_xor(s, off, 64);
    q += __shfl_xor(q, off, 64);
  }
  if ((tid & 63) == 0) { red[tid >> 6] = s; red[4 + (tid >> 6)] = q; }
  __syncthreads();
  s = red[0] + red[1] + red[2] + red[3];
  q = red[4] + red[5] + red[6] + red[7];
  const float mu = s * (1.f / DM);
  const float var = q * (1.f / DM) - mu * mu;
  const float rstd = rsqrtf(fmaxf(var, 0.f) + 1e-5f);

  f32x4 gv = *(const f32x4*)(g + tid * 4);
  f32x4 bv = *(const f32x4*)(be + tid * 4);
  f32x4 of;
#pragma unroll
  for (int j = 0; j < 4; j++) of[j] = (v[j] - mu) * rstd * gv[j] + bv[j];
  *(f32x4*)(O + base) = of;
}

// -------------------------------------------------------------------------------
extern "C" void kernel_launch(void* const* d_in, const int* in_sizes, int n_in,
                              void* d_out, int out_size, void* d_ws, size_t ws_size,
                              hipStream_t stream) {
  const float* src = (const float*)d_in[0];
  const float* wq  = (const float*)d_in[1];
  const float* bq  = (const float*)d_in[2];
  const float* wk  = (const float*)d_in[3];
  const float* bk  = (const float*)d_in[4];
  const float* wv  = (const float*)d_in[5];
  const float* bv  = (const float*)d_in[6];
  const float* g1  = (const float*)d_in[7];
  const float* be1 = (const float*)d_in[8];
  const float* w1  = (const float*)d_in[9];
  const float* b1  = (const float*)d_in[10];
  const float* w2  = (const float*)d_in[11];
  const float* b2  = (const float*)d_in[12];
  const float* g2  = (const float*)d_in[13];
  const float* be2 = (const float*)d_in[14];
  float* out = (float*)d_out;

  char* ws = (char*)d_ws;
  const size_t MB = 1024 * 1024;
  unsigned short* srcb  = (unsigned short*)(ws + 0);          //  8MB
  unsigned short* WqkvT = (unsigned short*)(ws + 8 * MB);     //  6MB
  float*          bqkv  = (float*)(ws + 14 * MB);             // 12KB
  unsigned short* W1T   = (unsigned short*)(ws + 15 * MB);    //  8MB
  unsigned short* W2T   = (unsigned short*)(ws + 23 * MB);    //  8MB
  unsigned short* QKV   = (unsigned short*)(ws + 31 * MB);    // 24MB
  unsigned short* Vtb   = (unsigned short*)(ws + 55 * MB);    //  8MB
  unsigned short* CTX   = (unsigned short*)(ws + 63 * MB);    //  8MB
  unsigned short* X1    = (unsigned short*)(ws + 71 * MB);    //  8MB
  float*          X1f   = (float*)(ws + 79 * MB);             // 16MB -> 95MB
  unsigned short* Hb    = (unsigned short*)(ws + 31 * MB);    // 32MB (QKV+Vtb dead)
  unsigned short* Pk0   = (unsigned short*)(ws + 0);          //  8MB (srcb dead)
  unsigned short* Pk1   = (unsigned short*)(ws + 15 * MB);    //  8MB (W1T dead)
  unsigned short* Pk2   = (unsigned short*)(ws + 63 * MB);    //  8MB (CTX dead)
  unsigned short* Pk3   = (unsigned short*)(ws + 71 * MB);    //  8MB (X1 dead)
  if (ws_size < 95 * MB) return;

  const dim3 t32(32, 8, 1);
  f32_to_bf16<<<4096, 256, 0, stream>>>(src, srcb, (long)NTOK * DM);
  transpose_f2b<<<dim3(32, 32), t32, 0, stream>>>(wq, 1024, WqkvT, 1024);
  transpose_f2b<<<dim3(32, 32), t32, 0, stream>>>(wk, 1024, WqkvT + 1024 * 1024, 1024);
  transpose_f2b<<<dim3(32, 32), t32, 0, stream>>>(wv, 1024, WqkvT + 2 * 1024 * 1024, 1024);
  transpose_f2b<<<dim3(128, 32), t32, 0, stream>>>(w1, 4096, W1T, 1024);
  transpose_f2b<<<dim3(32, 128), t32, 0, stream>>>(w2, 1024, W2T, 4096);
  concat3<<<12, 256, 0, stream>>>(bq, bk, bv, bqkv);

  // QKV = src @ [wq|wk|wv] + bias : M=4096, N=3072, K=1024 -> 192 tiles
  gemm256<false, false><<<dim3(192, 1), 512, 0, stream>>>(
      srcb, 1024, WqkvT, 1024, bqkv, QKV, nullptr, nullptr, nullptr, 3072, 12);
  transpose_v<<<dim3(2, 16, 128), t32, 0, stream>>>(QKV, Vtb);
  attn_kernel<<<dim3(4, 128), 512, 0, stream>>>(QKV, Vtb, CTX);
  ln1_kernel<<<NTOK, 256, 0, stream>>>(CTX, src, g1, be1, X1f, X1);
  // h = relu(x @ w1 + b1) : M=4096, N=4096, K=1024 -> 256 tiles
  gemm256<true, false><<<dim3(256, 1), 512, 0, stream>>>(
      X1, 1024, W1T, 1024, b1, Hb, nullptr, nullptr, nullptr, 4096, 16);
  // y partials = h @ w2 (split-K 4x1024) : M=4096, N=1024 -> 64 tiles x 4
  gemm256<false, true><<<dim3(64, 4), 512, 0, stream>>>(
      Hb, 4096, W2T, 4096, nullptr, Pk0, Pk1, Pk2, Pk3, 1024, 4);
  // out = LN(sum(partials) + b2 + x)
  ln2_kernel<<<NTOK, 256, 0, stream>>>(Pk0, Pk1, Pk2, Pk3, b2, X1f, g2, be2, out);
}

// Round 7
// 195.663 us; speedup vs baseline: 1.0033x; 1.0033x over previous
//
#include <hip/hip_runtime.h>
#include <hip/hip_bf16.h>
#include <stdint.h>

#define DM   1024
#define FF   4096
#define NH   16
#define DK   64
#define SEQ  512
#define NTOK 4096

typedef __attribute__((ext_vector_type(8))) unsigned short ushort8;
typedef __attribute__((ext_vector_type(4))) unsigned short ushort4v;
typedef __attribute__((ext_vector_type(8))) short bf16x8;
typedef __attribute__((ext_vector_type(4))) float f32x4;

__device__ __forceinline__ float bf2f(unsigned short u) {
  union { unsigned int i; float f; } v; v.i = ((unsigned int)u) << 16; return v.f;
}
__device__ __forceinline__ unsigned short f2bf(float f) {
  union { float fl; unsigned int i; } v; v.fl = f;
  v.i += 0x7fffu + ((v.i >> 16) & 1u);   // RNE
  return (unsigned short)(v.i >> 16);
}

__device__ __forceinline__ void gload16(const unsigned short* g, unsigned short* l) {
  __builtin_amdgcn_global_load_lds(
      (const __attribute__((address_space(1))) unsigned int*)g,
      (__attribute__((address_space(3))) unsigned int*)l, 16, 0, 0);
}

// ---------------- f32 -> bf16 elementwise convert ------------------------------
__global__ __launch_bounds__(256)
void f32_to_bf16(const float* __restrict__ in, unsigned short* __restrict__ out,
                 long n) {
  long i = ((long)blockIdx.x * 256 + threadIdx.x) * 4;
  if (i + 3 < n) {
    f32x4 v = *(const f32x4*)(in + i);
    ushort4v o;
#pragma unroll
    for (int j = 0; j < 4; j++) o[j] = f2bf(v[j]);
    *(ushort4v*)(out + i) = o;
  }
}

// ---------------- transpose + convert: out[n][k](bf16) = in[k][n](f32) ---------
__global__ void transpose_f2b(const float* __restrict__ in, int ldin,
                              unsigned short* __restrict__ out, int ldout) {
  __shared__ unsigned short tile[32][33];
  const int tx = threadIdx.x, ty = threadIdx.y;
  const long r0 = (long)blockIdx.y * 32, c0 = (long)blockIdx.x * 32;
#pragma unroll
  for (int i = 0; i < 4; i++)
    tile[ty + i * 8][tx] = f2bf(in[(r0 + ty + i * 8) * ldin + c0 + tx]);
  __syncthreads();
#pragma unroll
  for (int i = 0; i < 4; i++)
    out[(c0 + ty + i * 8) * ldout + r0 + tx] = tile[tx][ty + i * 8];
}

// ---------------- V transpose per (b,h): Vt[bh][d][s] = V[b, s, h, d] (bf16) ---
__global__ void transpose_v(const unsigned short* __restrict__ QKV,
                            unsigned short* __restrict__ Vt) {
  __shared__ unsigned short tile[32][33];
  const int tx = threadIdx.x, ty = threadIdx.y;
  const int bh = blockIdx.z, b = bh >> 4, h = bh & 15;
  const int s0 = blockIdx.y * 32, d0 = blockIdx.x * 32;
  const unsigned short* inb = QKV + (long)(b * SEQ) * 3072 + 2048 + h * 64;
#pragma unroll
  for (int i = 0; i < 4; i++)
    tile[ty + i * 8][tx] = inb[(long)(s0 + ty + i * 8) * 3072 + d0 + tx];
  __syncthreads();
#pragma unroll
  for (int i = 0; i < 4; i++)
    Vt[(long)bh * (DK * SEQ) + (long)(d0 + ty + i * 8) * SEQ + s0 + tx] =
        tile[tx][ty + i * 8];
}

// ---------------- concat 3 f32 bias vectors ------------------------------------
__global__ void concat3(const float* __restrict__ a, const float* __restrict__ b,
                        const float* __restrict__ c, float* __restrict__ o) {
  int i = blockIdx.x * 256 + threadIdx.x;
  if (i < 3072)
    o[i] = (i < 1024) ? a[i] : ((i < 2048) ? b[i - 1024] : c[i - 2048]);
}

// ========== 256x256 BK=64 double-buffered FREE-RUN bf16 GEMM ====================
// 8 waves (2Mx4N), per-wave 128x64 out.  LDS 128KB: A/B each [2buf][2ks][256][32]
// with the proven zero-conflict slot swizzle (src pre-swizzle + ds_read swizzle).
// Per K-tile exactly TWO barriers:
//   {lgkmcnt(0)+bar}: WAR gate (reads of t-1 done) -> stage tile t+1 (8 gloads)
//   {vmcnt(8)+bar}  : RAW gate (tile t landed; the 8 newest loads stay in flight)
// then a barrier-free region: 24 ds_read_b128 + 64 MFMA, compiler-scheduled.
// Waves skew inside the free region -> LDS pipe and matrix pipe overlap
// (m97/m114 implicit wave overlap) without a hand-built phase interleave.
template <bool RELU, bool PARTIAL>
__global__ __launch_bounds__(512, 2)
void gemm256(const unsigned short* __restrict__ A, int lda,
             const unsigned short* __restrict__ B, int ldb,
             const float* __restrict__ bias,
             unsigned short* __restrict__ C,
             unsigned short* __restrict__ P1,
             unsigned short* __restrict__ P2,
             unsigned short* __restrict__ P3,
             int ldc, int nTN) {
  __shared__ unsigned short sm[65536];   // A: [0,32768), B: [32768,65536) elements
  const int tid = threadIdx.x;
  const int lane = tid & 63;
  const int wid = tid >> 6;
  const int wr = wid >> 2, wc = wid & 3;

  const unsigned int T = gridDim.x;
  const unsigned int q8 = T >> 3;
  const unsigned int x = blockIdx.x;
  const unsigned int swz = (x & 7) * q8 + (x >> 3);
  const long bm = (long)(swz / nTN) * 256;
  const long bn = (long)(swz % nTN) * 256;
  const long kbase = (long)blockIdx.y * 1024;

  f32x4 acc[8][4];
#pragma unroll
  for (int mf = 0; mf < 8; mf++)
#pragma unroll
    for (int nf = 0; nf < 4; nf++) acc[mf][nf] = f32x4{0.f, 0.f, 0.f, 0.f};

  // staging: 512 thr cover 128 rows x 32 cols (8KB) per gload call
  const int strow = tid >> 2;                                  // 0..127
  const int scol = (((tid & 3) ^ ((tid >> 3) & 3)) << 3);      // pre-swizzled src
  const unsigned short* pA = A + (bm + strow) * lda + kbase + scol;
  const unsigned short* pB = B + (bn + strow) * ldb + kbase + scol;
  unsigned short* dA = sm + tid * 8;
  unsigned short* dB = sm + 32768 + tid * 8;

  const int g = lane >> 4;
  int offA[8], offB[4];
#pragma unroll
  for (int mf = 0; mf < 8; mf++) {
    const int rm = wr * 128 + mf * 16 + (lane & 15);
    offA[mf] = rm * 32 + ((g ^ ((rm >> 1) & 3)) << 3);   // row*32 folds the rh*4096
  }
#pragma unroll
  for (int nf = 0; nf < 4; nf++) {
    const int rb = wc * 64 + nf * 16 + (lane & 15);
    offB[nf] = rb * 32 + ((g ^ ((rb >> 1) & 3)) << 3);
  }

  // one full K-tile stage = 8 gload16 (A ks0/ks1 x 2 row-halves, B likewise)
#define GSTAGE(kt, bu) do {                                                    \
    gload16(pA + (long)(kt) * 64,                       dA + (bu) * 16384);    \
    gload16(pA + (long)(kt) * 64 + 32,                  dA + (bu) * 16384 + 8192); \
    gload16(pA + (long)128 * lda + (long)(kt) * 64,     dA + (bu) * 16384 + 4096); \
    gload16(pA + (long)128 * lda + (long)(kt) * 64 + 32,dA + (bu) * 16384 + 12288); \
    gload16(pB + (long)(kt) * 64,                       dB + (bu) * 16384);    \
    gload16(pB + (long)(kt) * 64 + 32,                  dB + (bu) * 16384 + 8192); \
    gload16(pB + (long)128 * ldb + (long)(kt) * 64,     dB + (bu) * 16384 + 4096); \
    gload16(pB + (long)128 * ldb + (long)(kt) * 64 + 32,dB + (bu) * 16384 + 12288); \
  } while (0)
#define MF16(AR, BR, MO)                                                      \
  do {                                                                        \
    __builtin_amdgcn_s_setprio(1);                                            \
    _Pragma("unroll")                                                         \
    for (int mf = 0; mf < 4; mf++)                                            \
      _Pragma("unroll")                                                       \
      for (int nf = 0; nf < 4; nf++)                                          \
        acc[(MO) + mf][nf] = __builtin_amdgcn_mfma_f32_16x16x32_bf16(         \
            AR[mf], BR[nf], acc[(MO) + mf][nf], 0, 0, 0);                     \
    __builtin_amdgcn_s_setprio(0);                                            \
  } while (0)

  // prologue: stage tile 0 into buf 0
  GSTAGE(0, 0);

  for (int t = 0; t < 16; ++t) {
    const int c = t & 1, n2 = c ^ 1;
    const int k1 = (t + 1) & 15;   // tail wraps: restaged, never read (safe)
    // WAR gate: every wave's reads of tile t-1 (buf n2) are complete
    asm volatile("s_waitcnt lgkmcnt(0)\ns_barrier" ::: "memory");
    GSTAGE(k1, n2);
    // RAW gate: tile t's 8 loads landed (8 newest = tile t+1's stay in flight)
    asm volatile("s_waitcnt vmcnt(8)\ns_barrier" ::: "memory");

    const unsigned short* smA = sm + c * 16384;
    const unsigned short* smB = sm + 32768 + c * 16384;
    bf16x8 ar[4], br[4];
    // ---- ks slice 0 ----
#pragma unroll
    for (int nf = 0; nf < 4; nf++) br[nf] = *(const bf16x8*)(smB + offB[nf]);
#pragma unroll
    for (int mf = 0; mf < 4; mf++) ar[mf] = *(const bf16x8*)(smA + offA[mf]);
    MF16(ar, br, 0);
#pragma unroll
    for (int mf = 0; mf < 4; mf++) ar[mf] = *(const bf16x8*)(smA + offA[4 + mf]);
    MF16(ar, br, 4);
    // ---- ks slice 1 ----
#pragma unroll
    for (int nf = 0; nf < 4; nf++) br[nf] = *(const bf16x8*)(smB + 8192 + offB[nf]);
#pragma unroll
    for (int mf = 0; mf < 4; mf++) ar[mf] = *(const bf16x8*)(smA + 8192 + offA[mf]);
    MF16(ar, br, 0);
#pragma unroll
    for (int mf = 0; mf < 4; mf++) ar[mf] = *(const bf16x8*)(smA + 8192 + offA[4 + mf]);
    MF16(ar, br, 4);
  }
  asm volatile("s_waitcnt vmcnt(0)" ::: "memory");   // retire wrap-stage loads
#undef GSTAGE
#undef MF16

  unsigned short* Cw = C;
  if (PARTIAL) {
    const int kc = blockIdx.y;
    Cw = (kc == 0) ? C : (kc == 1) ? P1 : (kc == 2) ? P2 : P3;
  }
  const long r0 = bm + wr * 128 + ((lane >> 4) << 2);
  const int c0 = (int)bn + wc * 64 + (lane & 15);
#pragma unroll
  for (int nf = 0; nf < 4; nf++) {
    const int col = c0 + nf * 16;
    const float bv = PARTIAL ? 0.f : bias[col];
#pragma unroll
    for (int mf = 0; mf < 8; mf++) {
#pragma unroll
      for (int i = 0; i < 4; i++) {
        float v = acc[mf][nf][i] + bv;
        if (RELU) v = fmaxf(v, 0.f);
        Cw[(r0 + mf * 16 + i) * ldc + col] = f2bf(v);
      }
    }
  }
}

// =================== flash attention: 8 waves, static softmax ===================
__global__ __launch_bounds__(512)
void attn_kernel(const unsigned short* __restrict__ QKV,
                 const unsigned short* __restrict__ Vt,
                 unsigned short* __restrict__ CTX) {
  const int qt = blockIdx.x;          // 0..3
  const int bh = blockIdx.y;          // 0..127
  const int b = bh >> 4, h = bh & 15;
  const int tid = threadIdx.x;
  const int lane = tid & 63;
  const int wid = tid >> 6;           // 0..7

  __shared__ unsigned short Ks[64][72];
  __shared__ unsigned short Vs[64][72];
  __shared__ unsigned short Ps[8][16][72];

  const int qrow0 = qt * 128 + wid * 16;
  const unsigned short* Qb = QKV + (long)(b * SEQ + qrow0) * 3072 + h * 64;
  bf16x8 aq[2];
#pragma unroll
  for (int ks = 0; ks < 2; ks++)
    aq[ks] = *(const bf16x8*)(Qb + (long)(lane & 15) * 3072 + ks * 32 +
                              (lane >> 4) * 8);

  f32x4 acc_o[4];
#pragma unroll
  for (int n = 0; n < 4; n++) acc_o[n] = f32x4{0.f, 0.f, 0.f, 0.f};
  float rsum[4] = {0.f, 0.f, 0.f, 0.f};

  const int sr = tid >> 3;            // 0..63
  const int sc = (tid & 7) * 8;       // 0..56
  const unsigned short* Kg = QKV + (long)(b * SEQ) * 3072 + 1024 + h * 64 + sc;
  const unsigned short* Vg = Vt + (long)bh * (DK * SEQ) + (long)sr * SEQ + sc;

  ushort8 kr = *(const ushort8*)(Kg + (long)sr * 3072);
  ushort8 vr = *(const ushort8*)(Vg);

#pragma unroll
  for (int c = 0; c < 8; ++c) {
    __syncthreads();
    *(ushort8*)(&Ks[sr][sc]) = kr;
    *(ushort8*)(&Vs[sr][sc]) = vr;
    if (c < 7) {
      kr = *(const ushort8*)(Kg + (long)((c + 1) * 64 + sr) * 3072);
      vr = *(const ushort8*)(Vg + (c + 1) * 64);
    }
    __syncthreads();

    f32x4 s[4];
#pragma unroll
    for (int n = 0; n < 4; n++) s[n] = f32x4{0.f, 0.f, 0.f, 0.f};
#pragma unroll
    for (int ks = 0; ks < 2; ks++) {
      bf16x8 kf[4];
#pragma unroll
      for (int n = 0; n < 4; n++)
        kf[n] = *(const bf16x8*)(&Ks[n * 16 + (lane & 15)][ks * 32 + (lane >> 4) * 8]);
#pragma unroll
      for (int n = 0; n < 4; n++)
        s[n] = __builtin_amdgcn_mfma_f32_16x16x32_bf16(aq[ks], kf[n], s[n], 0, 0, 0);
    }

#pragma unroll
    for (int n = 0; n < 4; n++) {
#pragma unroll
      for (int i = 0; i < 4; i++) {
        const float p = __expf(s[n][i] * 0.125f);
        rsum[i] += p;
        Ps[wid][(lane >> 4) * 4 + i][n * 16 + (lane & 15)] = f2bf(p);
      }
    }

#pragma unroll
    for (int ks = 0; ks < 2; ks++) {
      bf16x8 pa = *(const bf16x8*)(&Ps[wid][lane & 15][ks * 32 + (lane >> 4) * 8]);
      bf16x8 vf[4];
#pragma unroll
      for (int n = 0; n < 4; n++)
        vf[n] = *(const bf16x8*)(&Vs[n * 16 + (lane & 15)][ks * 32 + (lane >> 4) * 8]);
#pragma unroll
      for (int n = 0; n < 4; n++)
        acc_o[n] = __builtin_amdgcn_mfma_f32_16x16x32_bf16(pa, vf[n], acc_o[n], 0, 0, 0);
    }
  }

#pragma unroll
  for (int i = 0; i < 4; i++) {
#pragma unroll
    for (int off = 1; off < 16; off <<= 1) rsum[i] += __shfl_xor(rsum[i], off, 64);
  }

  const long orow0 = (long)(b * SEQ + qrow0);
#pragma unroll
  for (int i = 0; i < 4; i++) {
    const float inv = 1.f / rsum[i];
    const long r = orow0 + (lane >> 4) * 4 + i;
#pragma unroll
    for (int n = 0; n < 4; n++)
      CTX[r * DM + h * 64 + n * 16 + (lane & 15)] = f2bf(acc_o[n][i] * inv);
  }
}

// ---------------- LN1: LN(X(bf16) + R(f32)); writes f32 + bf16 -----------------
__global__ __launch_bounds__(256)
void ln1_kernel(const unsigned short* __restrict__ X,
                const float* __restrict__ R,
                const float* __restrict__ g,
                const float* __restrict__ be,
                float* __restrict__ Of,
                unsigned short* __restrict__ Ob) {
  const int t = blockIdx.x;
  const int tid = threadIdx.x;
  const long base = (long)t * DM + tid * 4;
  __shared__ float red[8];

  ushort4v xv = *(const ushort4v*)(X + base);
  f32x4 rv = *(const f32x4*)(R + base);
  float v[4];
#pragma unroll
  for (int j = 0; j < 4; j++) v[j] = bf2f(xv[j]) + rv[j];
  float s = v[0] + v[1] + v[2] + v[3];
  float q = v[0] * v[0] + v[1] * v[1] + v[2] * v[2] + v[3] * v[3];
#pragma unroll
  for (int off = 1; off < 64; off <<= 1) {
    s += __shfl_xor(s, off, 64);
    q += __shfl_xor(q, off, 64);
  }
  if ((tid & 63) == 0) { red[tid >> 6] = s; red[4 + (tid >> 6)] = q; }
  __syncthreads();
  s = red[0] + red[1] + red[2] + red[3];
  q = red[4] + red[5] + red[6] + red[7];
  const float mu = s * (1.f / DM);
  const float var = q * (1.f / DM) - mu * mu;
  const float rstd = rsqrtf(fmaxf(var, 0.f) + 1e-5f);

  f32x4 gv = *(const f32x4*)(g + tid * 4);
  f32x4 bv = *(const f32x4*)(be + tid * 4);
  f32x4 of;
  ushort4v ob;
#pragma unroll
  for (int j = 0; j < 4; j++) {
    of[j] = (v[j] - mu) * rstd * gv[j] + bv[j];
    ob[j] = f2bf(of[j]);
  }
  *(f32x4*)(Of + base) = of;
  *(ushort4v*)(Ob + base) = ob;
}

// ---------------- LN2: LN(sum(4 bf16 partials) + b2 + X1f); writes f32 ---------
__global__ __launch_bounds__(256)
void ln2_kernel(const unsigned short* __restrict__ P0,
                const unsigned short* __restrict__ P1,
                const unsigned short* __restrict__ P2,
                const unsigned short* __restrict__ P3,
                const float* __restrict__ b2,
                const float* __restrict__ R,
                const float* __restrict__ g,
                const float* __restrict__ be,
                float* __restrict__ O) {
  const int t = blockIdx.x;
  const int tid = threadIdx.x;
  const long base = (long)t * DM + tid * 4;
  __shared__ float red[8];

  ushort4v p0 = *(const ushort4v*)(P0 + base);
  ushort4v p1 = *(const ushort4v*)(P1 + base);
  ushort4v p2 = *(const ushort4v*)(P2 + base);
  ushort4v p3 = *(const ushort4v*)(P3 + base);
  f32x4 bb = *(const f32x4*)(b2 + tid * 4);
  f32x4 rv = *(const f32x4*)(R + base);
  float v[4];
#pragma unroll
  for (int j = 0; j < 4; j++)
    v[j] = bf2f(p0[j]) + bf2f(p1[j]) + bf2f(p2[j]) + bf2f(p3[j]) + bb[j] + rv[j];
  float s = v[0] + v[1] + v[2] + v[3];
  float q = v[0] * v[0] + v[1] * v[1] + v[2] * v[2] + v[3] * v[3];
#pragma unroll
  for (int off = 1; off < 64; off <<= 1) {
    s += __shfl_xor(s, off, 64);
    q += __shfl_xor(q, off, 64);
  }
  if ((tid & 63) == 0) { red[tid >> 6] = s; red[4 + (tid >> 6)] = q; }
  __syncthreads();
  s = red[0] + red[1] + red[2] + red[3];
  q = red[4] + red[5] + red[6] + red[7];
  const float mu = s * (1.f / DM);
  const float var = q * (1.f / DM) - mu * mu;
  const float rstd = rsqrtf(fmaxf(var, 0.f) + 1e-5f);

  f32x4 gv = *(const f32x4*)(g + tid * 4);
  f32x4 bv = *(const f32x4*)(be + tid * 4);
  f32x4 of;
#pragma unroll
  for (int j = 0; j < 4; j++) of[j] = (v[j] - mu) * rstd * gv[j] + bv[j];
  *(f32x4*)(O + base) = of;
}

// -------------------------------------------------------------------------------
extern "C" void kernel_launch(void* const* d_in, const int* in_sizes, int n_in,
                              void* d_out, int out_size, void* d_ws, size_t ws_size,
                              hipStream_t stream) {
  const float* src = (const float*)d_in[0];
  const float* wq  = (const float*)d_in[1];
  const float* bq  = (const float*)d_in[2];
  const float* wk  = (const float*)d_in[3];
  const float* bk  = (const float*)d_in[4];
  const float* wv  = (const float*)d_in[5];
  const float* bv  = (const float*)d_in[6];
  const float* g1  = (const float*)d_in[7];
  const float* be1 = (const float*)d_in[8];
  const float* w1  = (const float*)d_in[9];
  const float* b1  = (const float*)d_in[10];
  const float* w2  = (const float*)d_in[11];
  const float* b2  = (const float*)d_in[12];
  const float* g2  = (const float*)d_in[13];
  const float* be2 = (const float*)d_in[14];
  float* out = (float*)d_out;

  char* ws = (char*)d_ws;
  const size_t MB = 1024 * 1024;
  unsigned short* srcb  = (unsigned short*)(ws + 0);          //  8MB
  unsigned short* WqkvT = (unsigned short*)(ws + 8 * MB);     //  6MB
  float*          bqkv  = (float*)(ws + 14 * MB);             // 12KB
  unsigned short* W1T   = (unsigned short*)(ws + 15 * MB);    //  8MB
  unsigned short* W2T   = (unsigned short*)(ws + 23 * MB);    //  8MB
  unsigned short* QKV   = (unsigned short*)(ws + 31 * MB);    // 24MB
  unsigned short* Vtb   = (unsigned short*)(ws + 55 * MB);    //  8MB
  unsigned short* CTX   = (unsigned short*)(ws + 63 * MB);    //  8MB
  unsigned short* X1    = (unsigned short*)(ws + 71 * MB);    //  8MB
  float*          X1f   = (float*)(ws + 79 * MB);             // 16MB -> 95MB
  unsigned short* Hb    = (unsigned short*)(ws + 31 * MB);    // 32MB (QKV+Vtb dead)
  unsigned short* Pk0   = (unsigned short*)(ws + 0);          //  8MB (srcb dead)
  unsigned short* Pk1   = (unsigned short*)(ws + 15 * MB);    //  8MB (W1T dead)
  unsigned short* Pk2   = (unsigned short*)(ws + 63 * MB);    //  8MB (CTX dead)
  unsigned short* Pk3   = (unsigned short*)(ws + 71 * MB);    //  8MB (X1 dead)
  if (ws_size < 95 * MB) return;

  const dim3 t32(32, 8, 1);
  f32_to_bf16<<<4096, 256, 0, stream>>>(src, srcb, (long)NTOK * DM);
  transpose_f2b<<<dim3(32, 32), t32, 0, stream>>>(wq, 1024, WqkvT, 1024);
  transpose_f2b<<<dim3(32, 32), t32, 0, stream>>>(wk, 1024, WqkvT + 1024 * 1024, 1024);
  transpose_f2b<<<dim3(32, 32), t32, 0, stream>>>(wv, 1024, WqkvT + 2 * 1024 * 1024, 1024);
  transpose_f2b<<<dim3(128, 32), t32, 0, stream>>>(w1, 4096, W1T, 1024);
  transpose_f2b<<<dim3(32, 128), t32, 0, stream>>>(w2, 1024, W2T, 4096);
  concat3<<<12, 256, 0, stream>>>(bq, bk, bv, bqkv);

  // QKV = src @ [wq|wk|wv] + bias : M=4096, N=3072, K=1024 -> 192 tiles
  gemm256<false, false><<<dim3(192, 1), 512, 0, stream>>>(
      srcb, 1024, WqkvT, 1024, bqkv, QKV, nullptr, nullptr, nullptr, 3072, 12);
  transpose_v<<<dim3(2, 16, 128), t32, 0, stream>>>(QKV, Vtb);
  attn_kernel<<<dim3(4, 128), 512, 0, stream>>>(QKV, Vtb, CTX);
  ln1_kernel<<<NTOK, 256, 0, stream>>>(CTX, src, g1, be1, X1f, X1);
  // h = relu(x @ w1 + b1) : M=4096, N=4096, K=1024 -> 256 tiles
  gemm256<true, false><<<dim3(256, 1), 512, 0, stream>>>(
      X1, 1024, W1T, 1024, b1, Hb, nullptr, nullptr, nullptr, 4096, 16);
  // y partials = h @ w2 (split-K 4x1024) : M=4096, N=1024 -> 64 tiles x 4
  gemm256<false, true><<<dim3(64, 4), 512, 0, stream>>>(
      Hb, 4096, W2T, 4096, nullptr, Pk0, Pk1, Pk2, Pk3, 1024, 4);
  // out = LN(sum(partials) + b2 + x)
  ln2_kernel<<<NTOK, 256, 0, stream>>>(Pk0, Pk1, Pk2, Pk3, b2, X1f, g2, be2, out);
}